// Round 13
// baseline (132.328 us; speedup 1.0000x reference)
//
#include <hip/hip_runtime.h>
#include <math.h>

#define N_NODES 4096
#define DIM 256
#define HEADS 4
#define HDIM 64
#define NEDGE 131072
#define MAXNBR 256
#define MASK_WORDS 128   // 4096 / 32

typedef __attribute__((ext_vector_type(8))) short short8;
typedef __attribute__((ext_vector_type(4))) float float4v;
typedef __attribute__((ext_vector_type(2))) float float2v;

__device__ inline unsigned short f2b(float f) {   // fp32 -> bf16 RNE
    unsigned u = __float_as_uint(f);
    unsigned r = u + 0x7fffu + ((u >> 16) & 1u);
    return (unsigned short)(r >> 16);
}
__device__ inline float bl(unsigned u) { return __uint_as_float(u << 16); }
__device__ inline float bh(unsigned u) { return __uint_as_float(u & 0xffff0000u); }

__device__ inline uint4 pack8(float4 a, float4 b) {
    uint4 w;
    w.x = (unsigned)f2b(a.x) | ((unsigned)f2b(a.y) << 16);
    w.y = (unsigned)f2b(a.z) | ((unsigned)f2b(a.w) << 16);
    w.z = (unsigned)f2b(b.x) | ((unsigned)f2b(b.y) << 16);
    w.w = (unsigned)f2b(b.z) | ((unsigned)f2b(b.w) << 16);
    return w;
}

#if __has_builtin(__builtin_amdgcn_cvt_pk_f32_fp8) && __has_builtin(__builtin_amdgcn_cvt_pk_fp8_f32)
template <bool HI>
__device__ inline float2v pk8(unsigned w) {
    return __builtin_amdgcn_cvt_pk_f32_fp8((int)w, HI);   // word-select is constexpr
}
__device__ inline unsigned char enc8(float v) {
    return (unsigned char)(__builtin_amdgcn_cvt_pk_fp8_f32(v, v, 0, false) & 0xff);
}
#else
// software e4m3fn fallback
__device__ inline unsigned char enc8(float f) {
    unsigned u = __float_as_uint(f);
    unsigned s = (u >> 24) & 0x80u;
    float a = fabsf(f);
    if (!(a >= 0.015625f)) return (unsigned char)s;
    if (a > 448.f) return (unsigned char)(s | 0x7E);
    unsigned r = u + 0x7FFFFu + ((u >> 20) & 1u);
    unsigned e8 = ((r >> 23) & 255u) - 120u;
    unsigned m = (r >> 20) & 7u;
    if (e8 >= 15u && m == 7u) return (unsigned char)(s | 0x7E);
    return (unsigned char)(s | (e8 << 3) | m);
}
__device__ inline float d8s(unsigned b) {
    unsigned e = (b >> 3) & 15u;
    unsigned bits = ((b & 0x80u) << 24) | ((e + 120u) << 23) | ((b & 7u) << 20);
    return e ? __uint_as_float(bits) : 0.f;
}
template <bool HI>
__device__ inline float2v pk8(unsigned w) {
    unsigned x = HI ? (w >> 16) : w;
    float2v r;
    r.x = d8s(x & 255u);
    r.y = d8s((x >> 8) & 255u);
    return r;
}
#endif

// ---------------- fused prep: w_in->bf16 | Wc,bc | edge scatter ----------------
// blocks 0..191: convert w_in; 192..447: Wc tile (192 also bc); 448..959: edge scatter.
__global__ __launch_bounds__(256)
void prep_kernel(const float* __restrict__ w_in,
                 const float* __restrict__ wp, const float* __restrict__ wout,
                 const float* __restrict__ bout, const float* __restrict__ bp,
                 const int* __restrict__ eidx, unsigned int* __restrict__ mask,
                 unsigned short* __restrict__ w_in_bf,
                 unsigned short* __restrict__ wc, float* __restrict__ bc) {
    const int b = blockIdx.x;
    const int tid = threadIdx.x;
    if (b < 192) {
        int t = b * 1024 + tid * 4;
        float4 v = *(const float4*)&w_in[t];
        ushort4 o;
        o.x = f2b(v.x); o.y = f2b(v.y); o.z = f2b(v.z); o.w = f2b(v.w);
        *(ushort4*)&w_in_bf[t] = o;
    } else if (b < 448) {
        int bb = b - 192;                // 0..255
        int i = (bb >> 4) * 16 + (tid >> 4);
        int j = (bb & 15) * 16 + (tid & 15);
        float a0 = 0.f, a1 = 0.f, a2 = 0.f, a3 = 0.f;
        for (int k = 0; k < 256; k += 4) {
            a0 = fmaf(wp[i * 256 + k + 0], wout[(k + 0) * 256 + j], a0);
            a1 = fmaf(wp[i * 256 + k + 1], wout[(k + 1) * 256 + j], a1);
            a2 = fmaf(wp[i * 256 + k + 2], wout[(k + 2) * 256 + j], a2);
            a3 = fmaf(wp[i * 256 + k + 3], wout[(k + 3) * 256 + j], a3);
        }
        wc[i * 256 + j] = f2b((a0 + a1) + (a2 + a3));
        if (bb == 0) {
            float b0 = bp[tid], b1 = 0.f, b2 = 0.f, b3 = 0.f;
            for (int k = 0; k < 256; k += 4) {
                b0 = fmaf(wp[tid * 256 + k + 0], bout[k + 0], b0);
                b1 = fmaf(wp[tid * 256 + k + 1], bout[k + 1], b1);
                b2 = fmaf(wp[tid * 256 + k + 2], bout[k + 2], b2);
                b3 = fmaf(wp[tid * 256 + k + 3], bout[k + 3], b3);
            }
            bc[tid] = (b0 + b1) + (b2 + b3);
        }
    } else {
        int t = (b - 448) * 256 + tid;   // one edge per thread
        int s = eidx[t];
        int d = eidx[NEDGE + t];
        atomicOr(&mask[s * MASK_WORDS + (d >> 5)], 1u << (d & 31));
        atomicOr(&mask[d * MASK_WORDS + (s >> 5)], 1u << (s & 31));
    }
}

// ---------------- GEMM1: qkv projection, A = fp32 x (converted in staging) ----
// -> q_bf [N][256] bf16 + kv8 [N][512] fp8. BM=BN=64, BK=64, 4 waves over M.
__global__ __launch_bounds__(256)
void gemm_qkv(const float* __restrict__ A, const unsigned short* __restrict__ B,
              const float* __restrict__ bias,
              unsigned short* __restrict__ q_bf, unsigned char* __restrict__ kv8) {
    __shared__ unsigned short As[64 * 64];
    __shared__ unsigned short Bs[64 * 64];
    const int tid  = threadIdx.x;
    const int lane = tid & 63;
    const int wave = tid >> 6;
    const int brow = blockIdx.y * 64;
    const int bcol = blockIdx.x * 64;
    const int K = DIM;

    float4v acc[4];
#pragma unroll
    for (int t = 0; t < 4; ++t) acc[t] = (float4v){0.f, 0.f, 0.f, 0.f};

    const int quad = lane >> 4;
    const int l16  = lane & 15;

    for (int k0 = 0; k0 < K; k0 += 64) {
        __syncthreads();
#pragma unroll
        for (int it = 0; it < 2; ++it) {
            int c = it * 256 + tid;
            int row = c >> 3;
            int col = c & 7;
            int sw  = col ^ (row & 7);
            float4 a0 = *(const float4*)&A[(size_t)(brow + row) * K + k0 + col * 8];
            float4 a1 = *(const float4*)&A[(size_t)(brow + row) * K + k0 + col * 8 + 4];
            uint4 va = pack8(a0, a1);
            uint4 vb = *(const uint4*)&B[(size_t)(bcol + row) * K + k0 + col * 8];
            *(uint4*)&As[row * 64 + sw * 8] = va;
            *(uint4*)&Bs[row * 64 + sw * 8] = vb;
        }
        __syncthreads();
#pragma unroll
        for (int kk = 0; kk < 2; ++kk) {
            short8 af, bf[4];
            {
                int row = wave * 16 + l16;
                int sw = (kk * 4 + quad) ^ (row & 7);
                af = *(const short8*)&As[row * 64 + sw * 8];
            }
#pragma unroll
            for (int nt = 0; nt < 4; ++nt) {
                int row = nt * 16 + l16;
                int sw = (kk * 4 + quad) ^ (row & 7);
                bf[nt] = *(const short8*)&Bs[row * 64 + sw * 8];
            }
#pragma unroll
            for (int nt = 0; nt < 4; ++nt)
                acc[nt] = __builtin_amdgcn_mfma_f32_16x16x32_bf16(af, bf[nt], acc[nt], 0, 0, 0);
        }
    }

#pragma unroll
    for (int nt = 0; nt < 4; ++nt) {
        int colg = bcol + nt * 16 + l16;
        float bsv = bias[colg];
#pragma unroll
        for (int reg = 0; reg < 4; ++reg) {
            int rowg = brow + wave * 16 + quad * 4 + reg;
            float v = acc[nt][reg] + bsv;
            if (colg < 256)
                q_bf[(size_t)rowg * 256 + colg] = f2b(v);
            else
                kv8[(size_t)rowg * 512 + (colg - 256)] = enc8(v);  // K: 0..255, V: 256..511
        }
    }
}

// ---------------- single-pass sparse attention, fp8 K/V + HW decode ----------------
__global__ __launch_bounds__(256)
void attn_sparse_kernel(const unsigned short* __restrict__ q_bf,
                        const unsigned char* __restrict__ kv8,
                        const unsigned int* __restrict__ mask,
                        unsigned short* __restrict__ ctx) {
    __shared__ unsigned int rowmask[MASK_WORDS];
    __shared__ int cols_s[MAXNBR];
    __shared__ int count_s;

    const int tid  = threadIdx.x;
    const int wave = tid >> 6;   // head
    const int lane = tid & 63;
    const int ng = lane >> 3;
    const int dg = lane & 7;
    const int i = blockIdx.x;
    const int h = wave;

    if (tid < MASK_WORDS) rowmask[tid] = mask[(size_t)i * MASK_WORDS + tid];

    float qf[8];
    {
        uint4 qv = *(const uint4*)&q_bf[(size_t)i * 256 + h * HDIM + dg * 8];
        qf[0] = bl(qv.x); qf[1] = bh(qv.x);
        qf[2] = bl(qv.y); qf[3] = bh(qv.y);
        qf[4] = bl(qv.z); qf[5] = bh(qv.z);
        qf[6] = bl(qv.w); qf[7] = bh(qv.w);
    }
    __syncthreads();

    if (wave == 0) {
        unsigned w0 = rowmask[lane * 2];
        unsigned w1 = rowmask[lane * 2 + 1];
        int wi = i >> 5;
        if (wi == lane * 2)     w0 |= 1u << (i & 31);   // self-loop
        if (wi == lane * 2 + 1) w1 |= 1u << (i & 31);
        int cnt = __popc(w0) + __popc(w1);
        int incl = cnt;
#pragma unroll
        for (int off = 1; off < 64; off <<= 1) {
            int v = __shfl_up(incl, off, 64);
            if (lane >= off) incl += v;
        }
        int c = incl - cnt;
        int total = __shfl(incl, 63, 64);
        while (w0) {
            int b = __ffs(w0) - 1;
            if (c < MAXNBR) cols_s[c] = lane * 64 + b;
            ++c; w0 &= w0 - 1u;
        }
        while (w1) {
            int b = __ffs(w1) - 1;
            if (c < MAXNBR) cols_s[c] = lane * 64 + 32 + b;
            ++c; w1 &= w1 - 1u;
        }
        if (lane == 0) count_s = total > MAXNBR ? MAXNBR : total;
    }
    __syncthreads();
    const int count = count_s;

    const unsigned char* kB = kv8 + h * HDIM + dg * 8;        // K slice base
    const unsigned char* vB = kv8 + 256 + h * HDIM + dg * 8;  // V slice base
    float a0 = 0.f, a1 = 0.f, a2 = 0.f, a3 = 0.f, a4 = 0.f, a5 = 0.f, a6 = 0.f, a7 = 0.f;
    float esum = 0.f;

    for (int t0 = 0; t0 < count; t0 += 16) {
        int tA = t0 + ng;
        int tB = t0 + 8 + ng;
        int jA = cols_s[min(tA, count - 1)];
        int jB = cols_s[min(tB, count - 1)];
        uint2 kA = *(const uint2*)&kB[(size_t)jA * 512];
        uint2 vA = *(const uint2*)&vB[(size_t)jA * 512];
        uint2 kBB = *(const uint2*)&kB[(size_t)jB * 512];
        uint2 vBB = *(const uint2*)&vB[(size_t)jB * 512];
        float2v kA0 = pk8<false>(kA.x), kA1 = pk8<true>(kA.x);
        float2v kA2 = pk8<false>(kA.y), kA3 = pk8<true>(kA.y);
        float2v kB0 = pk8<false>(kBB.x), kB1 = pk8<true>(kBB.x);
        float2v kB2 = pk8<false>(kBB.y), kB3 = pk8<true>(kBB.y);
        float sA = qf[0] * kA0.x + qf[1] * kA0.y + qf[2] * kA1.x + qf[3] * kA1.y
                 + qf[4] * kA2.x + qf[5] * kA2.y + qf[6] * kA3.x + qf[7] * kA3.y;
        float sB = qf[0] * kB0.x + qf[1] * kB0.y + qf[2] * kB1.x + qf[3] * kB1.y
                 + qf[4] * kB2.x + qf[5] * kB2.y + qf[6] * kB3.x + qf[7] * kB3.y;
        sA += __shfl_xor(sA, 1, 64);  sB += __shfl_xor(sB, 1, 64);
        sA += __shfl_xor(sA, 2, 64);  sB += __shfl_xor(sB, 2, 64);
        sA += __shfl_xor(sA, 4, 64);  sB += __shfl_xor(sB, 4, 64);
        float eA = (tA < count) ? __expf(sA * 0.125f) : 0.f;
        float eB = (tB < count) ? __expf(sB * 0.125f) : 0.f;
        esum += eA + eB;
        float2v vA0 = pk8<false>(vA.x), vA1 = pk8<true>(vA.x);
        float2v vA2 = pk8<false>(vA.y), vA3 = pk8<true>(vA.y);
        float2v vB0 = pk8<false>(vBB.x), vB1 = pk8<true>(vBB.x);
        float2v vB2 = pk8<false>(vBB.y), vB3 = pk8<true>(vBB.y);
        a0 = fmaf(eA, vA0.x, a0); a1 = fmaf(eA, vA0.y, a1);
        a2 = fmaf(eA, vA1.x, a2); a3 = fmaf(eA, vA1.y, a3);
        a4 = fmaf(eA, vA2.x, a4); a5 = fmaf(eA, vA2.y, a5);
        a6 = fmaf(eA, vA3.x, a6); a7 = fmaf(eA, vA3.y, a7);
        a0 = fmaf(eB, vB0.x, a0); a1 = fmaf(eB, vB0.y, a1);
        a2 = fmaf(eB, vB1.x, a2); a3 = fmaf(eB, vB1.y, a3);
        a4 = fmaf(eB, vB2.x, a4); a5 = fmaf(eB, vB2.y, a5);
        a6 = fmaf(eB, vB3.x, a6); a7 = fmaf(eB, vB3.y, a7);
    }
#pragma unroll
    for (int off = 8; off <= 32; off <<= 1) {
        esum += __shfl_xor(esum, off, 64);
        a0 += __shfl_xor(a0, off, 64); a1 += __shfl_xor(a1, off, 64);
        a2 += __shfl_xor(a2, off, 64); a3 += __shfl_xor(a3, off, 64);
        a4 += __shfl_xor(a4, off, 64); a5 += __shfl_xor(a5, off, 64);
        a6 += __shfl_xor(a6, off, 64); a7 += __shfl_xor(a7, off, 64);
    }
    if (ng == 0) {
        float inv = 1.0f / esum;
        uint4 w;
        w.x = (unsigned)f2b(a0 * inv) | ((unsigned)f2b(a1 * inv) << 16);
        w.y = (unsigned)f2b(a2 * inv) | ((unsigned)f2b(a3 * inv) << 16);
        w.z = (unsigned)f2b(a4 * inv) | ((unsigned)f2b(a5 * inv) << 16);
        w.w = (unsigned)f2b(a6 * inv) | ((unsigned)f2b(a7 * inv) << 16);
        *(uint4*)&ctx[(size_t)i * DIM + h * HDIM + dg * 8] = w;
    }
}

// ---------------- GEMM2 + residual + LayerNorm fused ----------------
__global__ __launch_bounds__(256)
void gemm_ln(const unsigned short* __restrict__ A, const unsigned short* __restrict__ B,
             const float* __restrict__ bc, const float* __restrict__ x,
             const float* __restrict__ gamma, const float* __restrict__ beta,
             float* __restrict__ out) {
    __shared__ unsigned short As[16 * 64];    // 2 KB
    __shared__ unsigned short Bs[256 * 64];   // 32 KB
    __shared__ float redS[16][4];
    __shared__ float redQ[16][4];
    const int tid  = threadIdx.x;
    const int lane = tid & 63;
    const int wave = tid >> 6;
    const int brow = blockIdx.x * 16;
    const int K = DIM;

    float4v acc[4];
#pragma unroll
    for (int t = 0; t < 4; ++t) acc[t] = (float4v){0.f, 0.f, 0.f, 0.f};

    const int quad = lane >> 4;
    const int l16  = lane & 15;

    for (int k0 = 0; k0 < K; k0 += 64) {
        __syncthreads();
#pragma unroll
        for (int it = 0; it < 8; ++it) {
            int c = it * 256 + tid;
            int row = c >> 3;
            int col = c & 7;
            int sw  = col ^ (row & 7);
            uint4 vb = *(const uint4*)&B[(size_t)row * K + k0 + col * 8];
            *(uint4*)&Bs[row * 64 + sw * 8] = vb;
        }
        if (tid < 128) {
            int row = tid >> 3;
            int col = tid & 7;
            int sw  = col ^ (row & 7);
            uint4 va = *(const uint4*)&A[(size_t)(brow + row) * K + k0 + col * 8];
            *(uint4*)&As[row * 64 + sw * 8] = va;
        }
        __syncthreads();
#pragma unroll
        for (int kk = 0; kk < 2; ++kk) {
            short8 af, bf[4];
            {
                int row = l16;
                int sw = (kk * 4 + quad) ^ (row & 7);
                af = *(const short8*)&As[row * 64 + sw * 8];
            }
#pragma unroll
            for (int nt = 0; nt < 4; ++nt) {
                int row = wave * 64 + nt * 16 + l16;
                int sw = (kk * 4 + quad) ^ (row & 7);
                bf[nt] = *(const short8*)&Bs[row * 64 + sw * 8];
            }
#pragma unroll
            for (int nt = 0; nt < 4; ++nt)
                acc[nt] = __builtin_amdgcn_mfma_f32_16x16x32_bf16(af, bf[nt], acc[nt], 0, 0, 0);
        }
    }

    float vals[4][4];
    float ps[4] = {0.f, 0.f, 0.f, 0.f};
    float pq[4] = {0.f, 0.f, 0.f, 0.f};
#pragma unroll
    for (int nt = 0; nt < 4; ++nt) {
        int colg = wave * 64 + nt * 16 + l16;
        float bcv = bc[colg];
#pragma unroll
        for (int reg = 0; reg < 4; ++reg) {
            int rowg = brow + quad * 4 + reg;
            float v = acc[nt][reg] + bcv + x[(size_t)rowg * 256 + colg];
            vals[nt][reg] = v;
            ps[reg] += v;
            pq[reg] += v * v;
        }
    }
#pragma unroll
    for (int off = 1; off <= 8; off <<= 1) {
#pragma unroll
        for (int reg = 0; reg < 4; ++reg) {
            ps[reg] += __shfl_xor(ps[reg], off, 64);
            pq[reg] += __shfl_xor(pq[reg], off, 64);
        }
    }
    if (l16 == 0) {
#pragma unroll
        for (int reg = 0; reg < 4; ++reg) {
            redS[quad * 4 + reg][wave] = ps[reg];
            redQ[quad * 4 + reg][wave] = pq[reg];
        }
    }
    __syncthreads();
#pragma unroll
    for (int reg = 0; reg < 4; ++reg) {
        int rowl = quad * 4 + reg;
        float s = redS[rowl][0] + redS[rowl][1] + redS[rowl][2] + redS[rowl][3];
        float q = redQ[rowl][0] + redQ[rowl][1] + redQ[rowl][2] + redQ[rowl][3];
        float mean = s * (1.f / 256.f);
        float var = q * (1.f / 256.f) - mean * mean;
        float rstd = rsqrtf(var + 1e-5f);
        int rowg = brow + rowl;
#pragma unroll
        for (int nt = 0; nt < 4; ++nt) {
            int colg = wave * 64 + nt * 16 + l16;
            out[(size_t)rowg * 256 + colg] =
                (vals[nt][reg] - mean) * rstd * gamma[colg] + beta[colg];
        }
    }
}

// ---------------- launch ----------------
extern "C" void kernel_launch(void* const* d_in, const int* in_sizes, int n_in,
                              void* d_out, int out_size, void* d_ws, size_t ws_size,
                              hipStream_t stream) {
    const float* x      = (const float*)d_in[0];
    const int*   eidx   = (const int*)d_in[1];
    const float* w_in   = (const float*)d_in[2];
    const float* b_in   = (const float*)d_in[3];
    const float* w_out  = (const float*)d_in[4];
    const float* b_out  = (const float*)d_in[5];
    const float* w_p    = (const float*)d_in[6];
    const float* b_p    = (const float*)d_in[7];
    const float* gamma  = (const float*)d_in[8];
    const float* beta   = (const float*)d_in[9];
    float* out = (float*)d_out;

    char* ws = (char*)d_ws;
    unsigned int*   mask    = (unsigned int*)(ws + 0);            // 2 MB
    unsigned short* q_bf    = (unsigned short*)(ws + 2097152);    // 2 MB
    unsigned char*  kv8     = (unsigned char*)(ws + 4194304);     // 2 MB (fp8 K|V compact)
    unsigned short* ctx_bf  = (unsigned short*)(ws + 6291456);    // 2 MB
    unsigned short* w_in_bf = (unsigned short*)(ws + 8388608);    // 384 KB
    unsigned short* wc_bf   = (unsigned short*)(ws + 8781824);    // 128 KB
    float*          bc      = (float*)(ws + 8912896);             // 1 KB

    // mask zero, then fused prep (w_in convert + Wc/bc + edge scatter)
    (void)hipMemsetAsync(mask, 0, N_NODES * MASK_WORDS * 4, stream);
    prep_kernel<<<960, 256, 0, stream>>>(w_in, w_p, w_out, b_out, b_p, eidx, mask,
                                         w_in_bf, wc_bf, bc);
    // qkv projection: A = fp32 x (converted in staging); q -> bf16, k|v -> fp8 compact
    {
        dim3 grid(768 / 64, N_NODES / 64);
        gemm_qkv<<<grid, 256, 0, stream>>>(x, w_in_bf, b_in, q_bf, kv8);
    }
    // sparse attention (fp8 K/V gather, HW decode) -> ctx bf16 [4096 x 256]
    attn_sparse_kernel<<<N_NODES, 256, 0, stream>>>(q_bf, kv8, mask, ctx_bf);
    // y = ctx @ Wc^T + bc + x, then LayerNorm -> out (fused)
    gemm_ln<<<N_NODES / 16, 256, 0, stream>>>(ctx_bf, wc_bf, bc, x, gamma, beta, out);
}

// Round 14
// 125.688 us; speedup vs baseline: 1.0528x; 1.0528x over previous
//
#include <hip/hip_runtime.h>
#include <math.h>

#define N_NODES 4096
#define DIM 256
#define HEADS 4
#define HDIM 64
#define NEDGE 131072
#define MAXNBR 256
#define MASK_WORDS 128   // 4096 / 32

typedef __attribute__((ext_vector_type(8))) short short8;
typedef __attribute__((ext_vector_type(4))) float float4v;
typedef __attribute__((ext_vector_type(2))) float float2v;

__device__ inline unsigned short f2b(float f) {   // fp32 -> bf16 RNE
    unsigned u = __float_as_uint(f);
    unsigned r = u + 0x7fffu + ((u >> 16) & 1u);
    return (unsigned short)(r >> 16);
}
__device__ inline float bl(unsigned u) { return __uint_as_float(u << 16); }
__device__ inline float bh(unsigned u) { return __uint_as_float(u & 0xffff0000u); }

__device__ inline uint4 pack8(float4 a, float4 b) {
    uint4 w;
    w.x = (unsigned)f2b(a.x) | ((unsigned)f2b(a.y) << 16);
    w.y = (unsigned)f2b(a.z) | ((unsigned)f2b(a.w) << 16);
    w.z = (unsigned)f2b(b.x) | ((unsigned)f2b(b.y) << 16);
    w.w = (unsigned)f2b(b.z) | ((unsigned)f2b(b.w) << 16);
    return w;
}

#if __has_builtin(__builtin_amdgcn_cvt_pk_f32_fp8) && __has_builtin(__builtin_amdgcn_cvt_pk_fp8_f32)
template <bool HI>
__device__ inline float2v pk8(unsigned w) {
    return __builtin_amdgcn_cvt_pk_f32_fp8((int)w, HI);   // word-select is constexpr
}
__device__ inline unsigned char enc8(float v) {
    return (unsigned char)(__builtin_amdgcn_cvt_pk_fp8_f32(v, v, 0, false) & 0xff);
}
#else
// software e4m3fn fallback
__device__ inline unsigned char enc8(float f) {
    unsigned u = __float_as_uint(f);
    unsigned s = (u >> 24) & 0x80u;
    float a = fabsf(f);
    if (!(a >= 0.015625f)) return (unsigned char)s;
    if (a > 448.f) return (unsigned char)(s | 0x7E);
    unsigned r = u + 0x7FFFFu + ((u >> 20) & 1u);
    unsigned e8 = ((r >> 23) & 255u) - 120u;
    unsigned m = (r >> 20) & 7u;
    if (e8 >= 15u && m == 7u) return (unsigned char)(s | 0x7E);
    return (unsigned char)(s | (e8 << 3) | m);
}
__device__ inline float d8s(unsigned b) {
    unsigned e = (b >> 3) & 15u;
    unsigned bits = ((b & 0x80u) << 24) | ((e + 120u) << 23) | ((b & 7u) << 20);
    return e ? __uint_as_float(bits) : 0.f;
}
template <bool HI>
__device__ inline float2v pk8(unsigned w) {
    unsigned x = HI ? (w >> 16) : w;
    float2v r;
    r.x = d8s(x & 255u);
    r.y = d8s((x >> 8) & 255u);
    return r;
}
#endif

// ---------------- mega kernel: QKV GEMM | Wc,bc | edge scatter ----------------
// blocks 0..767: qkv projection (A=x fp32, B=w_in fp32, both converted in staging)
//   -> q_bf [N][256] bf16, kv8 [N][512] fp8 compact
// blocks 768..1023: Wc = W_p@W_out tile (block 768 also bc = W_p@b_out + b_p)
// blocks 1024..1535: edge scatter into mask (memset'd earlier on this stream)
__global__ __launch_bounds__(256)
void mega_kernel(const float* __restrict__ x, const float* __restrict__ w_in,
                 const float* __restrict__ b_in,
                 const float* __restrict__ wp, const float* __restrict__ wout,
                 const float* __restrict__ bout, const float* __restrict__ bp,
                 const int* __restrict__ eidx, unsigned int* __restrict__ mask,
                 unsigned short* __restrict__ q_bf, unsigned char* __restrict__ kv8,
                 unsigned short* __restrict__ wc, float* __restrict__ bc) {
    const int b = blockIdx.x;
    const int tid = threadIdx.x;

    if (b < 768) {
        // ---- QKV GEMM: BM=BN=64, BK=64, 4 waves over M ----
        __shared__ unsigned short As[64 * 64];
        __shared__ unsigned short Bs[64 * 64];
        const int lane = tid & 63;
        const int wave = tid >> 6;
        const int bx = b % 12;            // 12 column tiles (768 cols)
        const int by = b / 12;            // 64 row tiles
        const int brow = by * 64;
        const int bcol = bx * 64;
        const int K = DIM;

        float4v acc[4];
#pragma unroll
        for (int t = 0; t < 4; ++t) acc[t] = (float4v){0.f, 0.f, 0.f, 0.f};

        const int quad = lane >> 4;
        const int l16  = lane & 15;

        for (int k0 = 0; k0 < K; k0 += 64) {
            __syncthreads();
#pragma unroll
            for (int it = 0; it < 2; ++it) {
                int c = it * 256 + tid;
                int row = c >> 3;
                int col = c & 7;
                int sw  = col ^ (row & 7);
                float4 a0 = *(const float4*)&x[(size_t)(brow + row) * K + k0 + col * 8];
                float4 a1 = *(const float4*)&x[(size_t)(brow + row) * K + k0 + col * 8 + 4];
                float4 b0 = *(const float4*)&w_in[(size_t)(bcol + row) * K + k0 + col * 8];
                float4 b1 = *(const float4*)&w_in[(size_t)(bcol + row) * K + k0 + col * 8 + 4];
                *(uint4*)&As[row * 64 + sw * 8] = pack8(a0, a1);
                *(uint4*)&Bs[row * 64 + sw * 8] = pack8(b0, b1);
            }
            __syncthreads();
#pragma unroll
            for (int kk = 0; kk < 2; ++kk) {
                short8 af, bf[4];
                {
                    int row = wave * 16 + l16;
                    int sw = (kk * 4 + quad) ^ (row & 7);
                    af = *(const short8*)&As[row * 64 + sw * 8];
                }
#pragma unroll
                for (int nt = 0; nt < 4; ++nt) {
                    int row = nt * 16 + l16;
                    int sw = (kk * 4 + quad) ^ (row & 7);
                    bf[nt] = *(const short8*)&Bs[row * 64 + sw * 8];
                }
#pragma unroll
                for (int nt = 0; nt < 4; ++nt)
                    acc[nt] = __builtin_amdgcn_mfma_f32_16x16x32_bf16(af, bf[nt], acc[nt], 0, 0, 0);
            }
        }

#pragma unroll
        for (int nt = 0; nt < 4; ++nt) {
            int colg = bcol + nt * 16 + l16;
            float bsv = b_in[colg];
#pragma unroll
            for (int reg = 0; reg < 4; ++reg) {
                int rowg = brow + wave * 16 + quad * 4 + reg;
                float v = acc[nt][reg] + bsv;
                if (colg < 256)
                    q_bf[(size_t)rowg * 256 + colg] = f2b(v);
                else
                    kv8[(size_t)rowg * 512 + (colg - 256)] = enc8(v);
            }
        }
    } else if (b < 1024) {
        // ---- Wc tile ----
        int bb = b - 768;                 // 0..255
        int i = (bb >> 4) * 16 + (tid >> 4);
        int j = (bb & 15) * 16 + (tid & 15);
        float a0 = 0.f, a1 = 0.f, a2 = 0.f, a3 = 0.f;
        for (int k = 0; k < 256; k += 4) {
            a0 = fmaf(wp[i * 256 + k + 0], wout[(k + 0) * 256 + j], a0);
            a1 = fmaf(wp[i * 256 + k + 1], wout[(k + 1) * 256 + j], a1);
            a2 = fmaf(wp[i * 256 + k + 2], wout[(k + 2) * 256 + j], a2);
            a3 = fmaf(wp[i * 256 + k + 3], wout[(k + 3) * 256 + j], a3);
        }
        wc[i * 256 + j] = f2b((a0 + a1) + (a2 + a3));
        if (bb == 0) {
            float b0 = bp[tid], b1 = 0.f, b2 = 0.f, b3 = 0.f;
            for (int k = 0; k < 256; k += 4) {
                b0 = fmaf(wp[tid * 256 + k + 0], bout[k + 0], b0);
                b1 = fmaf(wp[tid * 256 + k + 1], bout[k + 1], b1);
                b2 = fmaf(wp[tid * 256 + k + 2], bout[k + 2], b2);
                b3 = fmaf(wp[tid * 256 + k + 3], bout[k + 3], b3);
            }
            bc[tid] = (b0 + b1) + (b2 + b3);
        }
    } else {
        // ---- edge scatter ----
        int t = (b - 1024) * 256 + tid;   // one edge per thread
        int s = eidx[t];
        int d = eidx[NEDGE + t];
        atomicOr(&mask[s * MASK_WORDS + (d >> 5)], 1u << (d & 31));
        atomicOr(&mask[d * MASK_WORDS + (s >> 5)], 1u << (s & 31));
    }
}

// ---------------- single-pass sparse attention, fp8 K/V + HW decode ----------------
// Block per query row; wave = head; lane=(ng,dg). Wave 0 extracts CSR from the
// global mask row (coalesced uint2/lane); one barrier; fused score+softmax+PV loop.
__global__ __launch_bounds__(256)
void attn_sparse_kernel(const unsigned short* __restrict__ q_bf,
                        const unsigned char* __restrict__ kv8,
                        const unsigned int* __restrict__ mask,
                        unsigned short* __restrict__ ctx) {
    __shared__ int cols_s[MAXNBR];
    __shared__ int count_s;

    const int tid  = threadIdx.x;
    const int wave = tid >> 6;   // head
    const int lane = tid & 63;
    const int ng = lane >> 3;
    const int dg = lane & 7;
    const int i = blockIdx.x;
    const int h = wave;

    float qf[8];
    {
        uint4 qv = *(const uint4*)&q_bf[(size_t)i * 256 + h * HDIM + dg * 8];
        qf[0] = bl(qv.x); qf[1] = bh(qv.x);
        qf[2] = bl(qv.y); qf[3] = bh(qv.y);
        qf[4] = bl(qv.z); qf[5] = bh(qv.z);
        qf[6] = bl(qv.w); qf[7] = bh(qv.w);
    }

    if (wave == 0) {
        uint2 mw = *(const uint2*)&mask[(size_t)i * MASK_WORDS + lane * 2];
        unsigned w0 = mw.x;
        unsigned w1 = mw.y;
        int wi = i >> 5;
        if (wi == lane * 2)     w0 |= 1u << (i & 31);   // self-loop
        if (wi == lane * 2 + 1) w1 |= 1u << (i & 31);
        int cnt = __popc(w0) + __popc(w1);
        int incl = cnt;
#pragma unroll
        for (int off = 1; off < 64; off <<= 1) {
            int v = __shfl_up(incl, off, 64);
            if (lane >= off) incl += v;
        }
        int c = incl - cnt;
        int total = __shfl(incl, 63, 64);
        while (w0) {
            int b = __ffs(w0) - 1;
            if (c < MAXNBR) cols_s[c] = lane * 64 + b;
            ++c; w0 &= w0 - 1u;
        }
        while (w1) {
            int b = __ffs(w1) - 1;
            if (c < MAXNBR) cols_s[c] = lane * 64 + 32 + b;
            ++c; w1 &= w1 - 1u;
        }
        if (lane == 0) count_s = total > MAXNBR ? MAXNBR : total;
    }
    __syncthreads();
    const int count = count_s;

    const unsigned char* kB = kv8 + h * HDIM + dg * 8;        // K slice base
    const unsigned char* vB = kv8 + 256 + h * HDIM + dg * 8;  // V slice base
    float a0 = 0.f, a1 = 0.f, a2 = 0.f, a3 = 0.f, a4 = 0.f, a5 = 0.f, a6 = 0.f, a7 = 0.f;
    float esum = 0.f;

    for (int t0 = 0; t0 < count; t0 += 16) {
        int tA = t0 + ng;
        int tB = t0 + 8 + ng;
        int jA = cols_s[min(tA, count - 1)];
        int jB = cols_s[min(tB, count - 1)];
        uint2 kA = *(const uint2*)&kB[(size_t)jA * 512];
        uint2 vA = *(const uint2*)&vB[(size_t)jA * 512];
        uint2 kBB = *(const uint2*)&kB[(size_t)jB * 512];
        uint2 vBB = *(const uint2*)&vB[(size_t)jB * 512];
        float2v kA0 = pk8<false>(kA.x), kA1 = pk8<true>(kA.x);
        float2v kA2 = pk8<false>(kA.y), kA3 = pk8<true>(kA.y);
        float2v kB0 = pk8<false>(kBB.x), kB1 = pk8<true>(kBB.x);
        float2v kB2 = pk8<false>(kBB.y), kB3 = pk8<true>(kBB.y);
        float sA = qf[0] * kA0.x + qf[1] * kA0.y + qf[2] * kA1.x + qf[3] * kA1.y
                 + qf[4] * kA2.x + qf[5] * kA2.y + qf[6] * kA3.x + qf[7] * kA3.y;
        float sB = qf[0] * kB0.x + qf[1] * kB0.y + qf[2] * kB1.x + qf[3] * kB1.y
                 + qf[4] * kB2.x + qf[5] * kB2.y + qf[6] * kB3.x + qf[7] * kB3.y;
        sA += __shfl_xor(sA, 1, 64);  sB += __shfl_xor(sB, 1, 64);
        sA += __shfl_xor(sA, 2, 64);  sB += __shfl_xor(sB, 2, 64);
        sA += __shfl_xor(sA, 4, 64);  sB += __shfl_xor(sB, 4, 64);
        float eA = (tA < count) ? __expf(sA * 0.125f) : 0.f;
        float eB = (tB < count) ? __expf(sB * 0.125f) : 0.f;
        esum += eA + eB;
        float2v vA0 = pk8<false>(vA.x), vA1 = pk8<true>(vA.x);
        float2v vA2 = pk8<false>(vA.y), vA3 = pk8<true>(vA.y);
        float2v vB0 = pk8<false>(vBB.x), vB1 = pk8<true>(vBB.x);
        float2v vB2 = pk8<false>(vBB.y), vB3 = pk8<true>(vBB.y);
        a0 = fmaf(eA, vA0.x, a0); a1 = fmaf(eA, vA0.y, a1);
        a2 = fmaf(eA, vA1.x, a2); a3 = fmaf(eA, vA1.y, a3);
        a4 = fmaf(eA, vA2.x, a4); a5 = fmaf(eA, vA2.y, a5);
        a6 = fmaf(eA, vA3.x, a6); a7 = fmaf(eA, vA3.y, a7);
        a0 = fmaf(eB, vB0.x, a0); a1 = fmaf(eB, vB0.y, a1);
        a2 = fmaf(eB, vB1.x, a2); a3 = fmaf(eB, vB1.y, a3);
        a4 = fmaf(eB, vB2.x, a4); a5 = fmaf(eB, vB2.y, a5);
        a6 = fmaf(eB, vB3.x, a6); a7 = fmaf(eB, vB3.y, a7);
    }
#pragma unroll
    for (int off = 8; off <= 32; off <<= 1) {
        esum += __shfl_xor(esum, off, 64);
        a0 += __shfl_xor(a0, off, 64); a1 += __shfl_xor(a1, off, 64);
        a2 += __shfl_xor(a2, off, 64); a3 += __shfl_xor(a3, off, 64);
        a4 += __shfl_xor(a4, off, 64); a5 += __shfl_xor(a5, off, 64);
        a6 += __shfl_xor(a6, off, 64); a7 += __shfl_xor(a7, off, 64);
    }
    if (ng == 0) {
        float inv = 1.0f / esum;
        uint4 w;
        w.x = (unsigned)f2b(a0 * inv) | ((unsigned)f2b(a1 * inv) << 16);
        w.y = (unsigned)f2b(a2 * inv) | ((unsigned)f2b(a3 * inv) << 16);
        w.z = (unsigned)f2b(a4 * inv) | ((unsigned)f2b(a5 * inv) << 16);
        w.w = (unsigned)f2b(a6 * inv) | ((unsigned)f2b(a7 * inv) << 16);
        *(uint4*)&ctx[(size_t)i * DIM + h * HDIM + dg * 8] = w;
    }
}

// ---------------- GEMM2 + residual + LayerNorm fused ----------------
__global__ __launch_bounds__(256)
void gemm_ln(const unsigned short* __restrict__ A, const unsigned short* __restrict__ B,
             const float* __restrict__ bc, const float* __restrict__ x,
             const float* __restrict__ gamma, const float* __restrict__ beta,
             float* __restrict__ out) {
    __shared__ unsigned short As[16 * 64];    // 2 KB
    __shared__ unsigned short Bs[256 * 64];   // 32 KB
    __shared__ float redS[16][4];
    __shared__ float redQ[16][4];
    const int tid  = threadIdx.x;
    const int lane = tid & 63;
    const int wave = tid >> 6;
    const int brow = blockIdx.x * 16;
    const int K = DIM;

    float4v acc[4];
#pragma unroll
    for (int t = 0; t < 4; ++t) acc[t] = (float4v){0.f, 0.f, 0.f, 0.f};

    const int quad = lane >> 4;
    const int l16  = lane & 15;

    for (int k0 = 0; k0 < K; k0 += 64) {
        __syncthreads();
#pragma unroll
        for (int it = 0; it < 8; ++it) {
            int c = it * 256 + tid;
            int row = c >> 3;
            int col = c & 7;
            int sw  = col ^ (row & 7);
            uint4 vb = *(const uint4*)&B[(size_t)row * K + k0 + col * 8];
            *(uint4*)&Bs[row * 64 + sw * 8] = vb;
        }
        if (tid < 128) {
            int row = tid >> 3;
            int col = tid & 7;
            int sw  = col ^ (row & 7);
            uint4 va = *(const uint4*)&A[(size_t)(brow + row) * K + k0 + col * 8];
            *(uint4*)&As[row * 64 + sw * 8] = va;
        }
        __syncthreads();
#pragma unroll
        for (int kk = 0; kk < 2; ++kk) {
            short8 af, bf[4];
            {
                int row = l16;
                int sw = (kk * 4 + quad) ^ (row & 7);
                af = *(const short8*)&As[row * 64 + sw * 8];
            }
#pragma unroll
            for (int nt = 0; nt < 4; ++nt) {
                int row = wave * 64 + nt * 16 + l16;
                int sw = (kk * 4 + quad) ^ (row & 7);
                bf[nt] = *(const short8*)&Bs[row * 64 + sw * 8];
            }
#pragma unroll
            for (int nt = 0; nt < 4; ++nt)
                acc[nt] = __builtin_amdgcn_mfma_f32_16x16x32_bf16(af, bf[nt], acc[nt], 0, 0, 0);
        }
    }

    float vals[4][4];
    float ps[4] = {0.f, 0.f, 0.f, 0.f};
    float pq[4] = {0.f, 0.f, 0.f, 0.f};
#pragma unroll
    for (int nt = 0; nt < 4; ++nt) {
        int colg = wave * 64 + nt * 16 + l16;
        float bcv = bc[colg];
#pragma unroll
        for (int reg = 0; reg < 4; ++reg) {
            int rowg = brow + quad * 4 + reg;
            float v = acc[nt][reg] + bcv + x[(size_t)rowg * 256 + colg];
            vals[nt][reg] = v;
            ps[reg] += v;
            pq[reg] += v * v;
        }
    }
#pragma unroll
    for (int off = 1; off <= 8; off <<= 1) {
#pragma unroll
        for (int reg = 0; reg < 4; ++reg) {
            ps[reg] += __shfl_xor(ps[reg], off, 64);
            pq[reg] += __shfl_xor(pq[reg], off, 64);
        }
    }
    if (l16 == 0) {
#pragma unroll
        for (int reg = 0; reg < 4; ++reg) {
            redS[quad * 4 + reg][wave] = ps[reg];
            redQ[quad * 4 + reg][wave] = pq[reg];
        }
    }
    __syncthreads();
#pragma unroll
    for (int reg = 0; reg < 4; ++reg) {
        int rowl = quad * 4 + reg;
        float s = redS[rowl][0] + redS[rowl][1] + redS[rowl][2] + redS[rowl][3];
        float q = redQ[rowl][0] + redQ[rowl][1] + redQ[rowl][2] + redQ[rowl][3];
        float mean = s * (1.f / 256.f);
        float var = q * (1.f / 256.f) - mean * mean;
        float rstd = rsqrtf(var + 1e-5f);
        int rowg = brow + rowl;
#pragma unroll
        for (int nt = 0; nt < 4; ++nt) {
            int colg = wave * 64 + nt * 16 + l16;
            out[(size_t)rowg * 256 + colg] =
                (vals[nt][reg] - mean) * rstd * gamma[colg] + beta[colg];
        }
    }
}

// ---------------- launch ----------------
extern "C" void kernel_launch(void* const* d_in, const int* in_sizes, int n_in,
                              void* d_out, int out_size, void* d_ws, size_t ws_size,
                              hipStream_t stream) {
    const float* x      = (const float*)d_in[0];
    const int*   eidx   = (const int*)d_in[1];
    const float* w_in   = (const float*)d_in[2];
    const float* b_in   = (const float*)d_in[3];
    const float* w_out  = (const float*)d_in[4];
    const float* b_out  = (const float*)d_in[5];
    const float* w_p    = (const float*)d_in[6];
    const float* b_p    = (const float*)d_in[7];
    const float* gamma  = (const float*)d_in[8];
    const float* beta   = (const float*)d_in[9];
    float* out = (float*)d_out;

    char* ws = (char*)d_ws;
    unsigned int*   mask    = (unsigned int*)(ws + 0);            // 2 MB
    unsigned short* q_bf    = (unsigned short*)(ws + 2097152);    // 2 MB
    unsigned char*  kv8     = (unsigned char*)(ws + 4194304);     // 2 MB (fp8 K|V compact)
    unsigned short* ctx_bf  = (unsigned short*)(ws + 6291456);    // 2 MB
    unsigned short* wc_bf   = (unsigned short*)(ws + 8388608);    // 128 KB
    float*          bc      = (float*)(ws + 8519680);             // 1 KB

    // 1. mask zero
    (void)hipMemsetAsync(mask, 0, N_NODES * MASK_WORDS * 4, stream);
    // 2. mega: qkv GEMM (fp32 inputs, staged convert) | Wc/bc | edge scatter
    mega_kernel<<<1536, 256, 0, stream>>>(x, w_in, b_in, w_p, w_out, b_out, b_p,
                                          eidx, mask, q_bf, kv8, wc_bf, bc);
    // 3. sparse attention (fp8 K/V gather, HW decode) -> ctx bf16
    attn_sparse_kernel<<<N_NODES, 256, 0, stream>>>(q_bf, kv8, mask, ctx_bf);
    // 4. y = ctx @ Wc^T + bc + x, then LayerNorm -> out (fused)
    gemm_ln<<<N_NODES / 16, 256, 0, stream>>>(ctx_bf, wc_bf, bc, x, gamma, beta, out);
}